// Round 2
// baseline (1198.878 us; speedup 1.0000x reference)
//
#include <hip/hip_runtime.h>
#include <hip/hip_bf16.h>
#include <cstdint>
#include <cstddef>

typedef __bf16 bf16_t;
typedef bf16_t bf16x8 __attribute__((ext_vector_type(8)));
typedef bf16_t bf16x4 __attribute__((ext_vector_type(4)));
typedef float f32x4 __attribute__((ext_vector_type(4)));

#define NEG_BIG (-1e30f)

// ---------------- fp32 -> bf16 convert with K padding ----------------
__global__ __launch_bounds__(256) void convert_pad(const float* __restrict__ src,
                                                   bf16_t* __restrict__ dst,
                                                   int incols, int outcols) {
    const int row = blockIdx.x;
    const float* s = src + (size_t)row * incols;
    bf16_t* d = dst + (size_t)row * outcols;
    const int n4 = outcols >> 2;
    for (int c = threadIdx.x; c < n4; c += blockDim.x) {
        const int col = c << 2;
        float4 v;
        if (col < incols) v = *(const float4*)(s + col);   // incols % 4 == 0
        else              v = make_float4(0.f, 0.f, 0.f, 0.f);
        bf16x4 o;
        o[0] = (bf16_t)v.x; o[1] = (bf16_t)v.y; o[2] = (bf16_t)v.z; o[3] = (bf16_t)v.w;
        *(bf16x4*)(d + col) = o;
    }
}

// ---------------- bf16 GEMM: Z = A[M,K] @ W[N,K]^T + bias, Z bf16 ----------------
// m97 structure: 128x128 tile, BK=32, global_load_lds width 16, ds_read_b128.
#define BM 128
#define BN 128
#define BK 32

__global__ __launch_bounds__(256) void gemm_bt(const bf16_t* __restrict__ A,
                                               const bf16_t* __restrict__ W,
                                               const float* __restrict__ bias,
                                               bf16_t* __restrict__ Z,
                                               int K, int N) {
    __shared__ __align__(16) bf16_t As[BM * BK];
    __shared__ __align__(16) bf16_t Bs[BN * BK];
    const int tid  = threadIdx.x;
    const int wid  = tid >> 6;
    const int lane = tid & 63;
    const int n0 = blockIdx.x * BN;
    const int m0 = blockIdx.y * BM;

    const int wm = (wid >> 1) * 64;   // wave row offset within tile
    const int wn = (wid & 1) * 64;    // wave col offset within tile

    f32x4 acc[4][4] = {};

    const int srow0 = wid * 32 + (lane >> 2);     // staging row, t=0; t=1 adds 16
    const int scol  = (lane & 3) * 8;             // element offset (8 bf16 = 16B)

    const bf16_t* Aptr0 = A + (size_t)(m0 + srow0) * K + scol;
    const bf16_t* Aptr1 = A + (size_t)(m0 + srow0 + 16) * K + scol;
    const bf16_t* Wptr0 = W + (size_t)(n0 + srow0) * K + scol;
    const bf16_t* Wptr1 = W + (size_t)(n0 + srow0 + 16) * K + scol;

    bf16_t* AsB0 = As + (wid * 2 + 0) * 512;   // wave-uniform LDS bases
    bf16_t* AsB1 = As + (wid * 2 + 1) * 512;
    bf16_t* BsB0 = Bs + (wid * 2 + 0) * 512;
    bf16_t* BsB1 = Bs + (wid * 2 + 1) * 512;

    for (int k0 = 0; k0 < K; k0 += BK) {
        __syncthreads();
        __builtin_amdgcn_global_load_lds((const __attribute__((address_space(1))) void*)(Aptr0 + k0),
                                         (__attribute__((address_space(3))) void*)AsB0, 16, 0, 0);
        __builtin_amdgcn_global_load_lds((const __attribute__((address_space(1))) void*)(Aptr1 + k0),
                                         (__attribute__((address_space(3))) void*)AsB1, 16, 0, 0);
        __builtin_amdgcn_global_load_lds((const __attribute__((address_space(1))) void*)(Wptr0 + k0),
                                         (__attribute__((address_space(3))) void*)BsB0, 16, 0, 0);
        __builtin_amdgcn_global_load_lds((const __attribute__((address_space(1))) void*)(Wptr1 + k0),
                                         (__attribute__((address_space(3))) void*)BsB1, 16, 0, 0);
        __syncthreads();

        const int arow = wm + (lane & 15);
        const int brow = wn + (lane & 15);
        const int koff = (lane >> 4) * 8;
        bf16x8 af[4], bfr[4];
        #pragma unroll
        for (int i = 0; i < 4; ++i)
            af[i] = *(const bf16x8*)(As + (arow + i * 16) * BK + koff);
        #pragma unroll
        for (int j = 0; j < 4; ++j)
            bfr[j] = *(const bf16x8*)(Bs + (brow + j * 16) * BK + koff);
        #pragma unroll
        for (int i = 0; i < 4; ++i)
            #pragma unroll
            for (int j = 0; j < 4; ++j)
                acc[i][j] = __builtin_amdgcn_mfma_f32_16x16x32_bf16(af[i], bfr[j], acc[i][j], 0, 0, 0);
    }

    // epilogue: C/D layout col=lane&15, row=(lane>>4)*4+r
    const int cq = lane >> 4;
    const int cl = lane & 15;
    #pragma unroll
    for (int j = 0; j < 4; ++j) {
        const int col = n0 + wn + j * 16 + cl;
        const float bj = bias[col];
        #pragma unroll
        for (int i = 0; i < 4; ++i) {
            const int row = m0 + wm + i * 16 + cq * 4;
            #pragma unroll
            for (int r = 0; r < 4; ++r)
                Z[(size_t)(row + r) * N + col] = (bf16_t)(acc[i][j][r] + bj);
        }
    }
}

// ---------------- mixed activation: ONE WAVE PER ROW, no barriers ----------------
// 256 threads = 4 waves = 4 rows per block; lane owns cols {c*256 + lane*4 + j}.
__device__ __forceinline__ float wave_max(float v) {
    #pragma unroll
    for (int off = 32; off > 0; off >>= 1) v = fmaxf(v, __shfl_xor(v, off));
    return v;
}
__device__ __forceinline__ float wave_sum(float v) {
    #pragma unroll
    for (int off = 32; off > 0; off >>= 1) v += __shfl_xor(v, off);
    return v;
}

__global__ __launch_bounds__(256) void act_kernel(const bf16_t* __restrict__ Z,
                                                  const float* __restrict__ mask,
                                                  const int* __restrict__ tids,
                                                  bf16_t* __restrict__ H,
                                                  float* __restrict__ mask_out) {
    const int wid  = threadIdx.x >> 6;
    const int lane = threadIdx.x & 63;
    const int row  = blockIdx.x * 4 + wid;
    const size_t rb = (size_t)row * 1024;

    float z[16], mk[16];
    int   ty[16];
    #pragma unroll
    for (int c = 0; c < 4; ++c) {
        const int col = c * 256 + lane * 4;
        const bf16x4 zv = *(const bf16x4*)(Z + rb + col);
        const float4 mv = *(const float4*)(mask + rb + col);
        const int4   tv = *(const int4*)(tids + col);
        z[c*4+0] = (float)zv[0]; z[c*4+1] = (float)zv[1];
        z[c*4+2] = (float)zv[2]; z[c*4+3] = (float)zv[3];
        mk[c*4+0] = mv.x; mk[c*4+1] = mv.y; mk[c*4+2] = mv.z; mk[c*4+3] = mv.w;
        ty[c*4+0] = tv.x; ty[c*4+1] = tv.y; ty[c*4+2] = tv.z; ty[c*4+3] = tv.w;
    }

    // reductions over tid==3 (softmax of z) and tid==4 (softmax of -z)
    float mx3 = NEG_BIG, mx4 = NEG_BIG;
    #pragma unroll
    for (int j = 0; j < 16; ++j) {
        if (ty[j] == 3) mx3 = fmaxf(mx3, z[j]);
        if (ty[j] == 4) mx4 = fmaxf(mx4, -z[j]);
    }
    mx3 = wave_max(mx3);
    mx4 = wave_max(mx4);

    float s3 = 0.f, s4 = 0.f;
    #pragma unroll
    for (int j = 0; j < 16; ++j) {
        if (ty[j] == 3) s3 += __expf(z[j] - mx3);
        if (ty[j] == 4) s4 += __expf(-z[j] - mx4);
    }
    s3 = wave_sum(s3);
    s4 = wave_sum(s4);
    const float inv3 = 1.f / s3;   // only consumed where ty==3
    const float inv4 = 1.f / s4;

    #pragma unroll
    for (int c = 0; c < 4; ++c) {
        const int col = c * 256 + lane * 4;
        bf16x4 h4;
        float4 m4;
        #pragma unroll
        for (int j = 0; j < 4; ++j) {
            const int k = c * 4 + j;
            const float zz = z[k];
            const int   tt = ty[k];
            float a;
            if (tt == 0)      a = fmaxf(zz, 0.f);
            else if (tt == 1) { const float e = __expf(-2.f * fabsf(zz));
                                const float th = (1.f - e) / (1.f + e);
                                a = (zz >= 0.f) ? th : -th; }
            else if (tt == 2) a = 1.f / (1.f + __expf(-zz));
            else if (tt == 3) a = __expf(zz - mx3) * inv3;
            else if (tt == 4) a = __expf(-zz - mx4) * inv4;
            else if (tt == 5) a = 0.5f * zz * (1.f + erff(zz * 0.70710678118654752f));
            else              a = (zz >= 0.f) ? zz : 0.01f * zz;
            h4[j] = (bf16_t)(a * mk[k] * 2.0f);   // KEEP_SCALE = 2
        }
        m4.x = mk[c*4+0]; m4.y = mk[c*4+1]; m4.z = mk[c*4+2]; m4.w = mk[c*4+3];
        *(bf16x4*)(H + rb + col) = h4;
        *(float4*)(mask_out + rb + col) = m4;
    }
}

// ---------------- final layer: logits = H @ W3^T + b3, then log_softmax ----------------
__global__ __launch_bounds__(256) void final_layer(const bf16_t* __restrict__ H,
                                                   const float* __restrict__ W3,
                                                   const float* __restrict__ b3,
                                                   float* __restrict__ out) {
    __shared__ __align__(16) bf16_t Ws[10 * 1024];
    for (int i = threadIdx.x; i < 10240; i += 256) Ws[i] = (bf16_t)W3[i];
    __syncthreads();
    const int wid  = threadIdx.x >> 6;
    const int lane = threadIdx.x & 63;
    #pragma unroll 1
    for (int rr = 0; rr < 4; ++rr) {
        const int row = blockIdx.x * 16 + wid * 4 + rr;
        const bf16_t* hrow = H + (size_t)row * 1024;
        float acc[10];
        #pragma unroll
        for (int n = 0; n < 10; ++n) acc[n] = 0.f;
        #pragma unroll
        for (int c = 0; c < 2; ++c) {
            const int k = c * 512 + lane * 8;
            const bf16x8 hv = *(const bf16x8*)(hrow + k);
            float hf[8];
            #pragma unroll
            for (int j = 0; j < 8; ++j) hf[j] = (float)hv[j];
            #pragma unroll
            for (int n = 0; n < 10; ++n) {
                const bf16x8 wv = *(const bf16x8*)(Ws + n * 1024 + k);
                #pragma unroll
                for (int j = 0; j < 8; ++j) acc[n] += hf[j] * (float)wv[j];
            }
        }
        #pragma unroll
        for (int n = 0; n < 10; ++n)
            #pragma unroll
            for (int off = 32; off > 0; off >>= 1)
                acc[n] += __shfl_down(acc[n], off);
        if (lane == 0) {
            float lg[10]; float mx = -1e30f;
            #pragma unroll
            for (int n = 0; n < 10; ++n) { lg[n] = acc[n] + b3[n]; mx = fmaxf(mx, lg[n]); }
            float se = 0.f;
            #pragma unroll
            for (int n = 0; n < 10; ++n) se += __expf(lg[n] - mx);
            const float lse = logf(se) + mx;
            #pragma unroll
            for (int n = 0; n < 10; ++n) out[(size_t)row * 10 + n] = lg[n] - lse;
        }
    }
}

extern "C" void kernel_launch(void* const* d_in, const int* in_sizes, int n_in,
                              void* d_out, int out_size, void* d_ws, size_t ws_size,
                              hipStream_t stream) {
    (void)in_sizes; (void)n_in; (void)out_size; (void)ws_size;
    const float* x     = (const float*)d_in[0];
    const float* W0    = (const float*)d_in[1];
    const float* b0    = (const float*)d_in[2];
    const float* W1    = (const float*)d_in[3];
    const float* b1    = (const float*)d_in[4];
    const float* W2    = (const float*)d_in[5];
    const float* b2    = (const float*)d_in[6];
    const float* W3    = (const float*)d_in[7];
    const float* b3    = (const float*)d_in[8];
    const float* mask1 = (const float*)d_in[9];
    const float* mask2 = (const float*)d_in[10];
    const float* mask3 = (const float*)d_in[11];
    const int*   tids  = (const int*)d_in[12];

    float* out = (float*)d_out;
    float* mo1 = out + 327680;               // 32768*10
    float* mo2 = mo1 + 33554432;             // 32768*1024
    float* mo3 = mo2 + 33554432;

    char* ws = (char*)d_ws;
    bf16_t* xb  = (bf16_t*)ws;  ws += (size_t)32768 * 800 * 2;
    bf16_t* W0b = (bf16_t*)ws;  ws += (size_t)1024 * 800 * 2;
    bf16_t* W1b = (bf16_t*)ws;  ws += (size_t)1024 * 1024 * 2;
    bf16_t* W2b = (bf16_t*)ws;  ws += (size_t)1024 * 1024 * 2;
    bf16_t* Zb  = (bf16_t*)ws;  ws += (size_t)32768 * 1024 * 2;
    bf16_t* hb  = (bf16_t*)ws;  ws += (size_t)32768 * 1024 * 2;

    convert_pad<<<32768, 256, 0, stream>>>(x,  xb,  784, 800);
    convert_pad<<<1024,  256, 0, stream>>>(W0, W0b, 784, 800);
    convert_pad<<<1024,  256, 0, stream>>>(W1, W1b, 1024, 1024);
    convert_pad<<<1024,  256, 0, stream>>>(W2, W2b, 1024, 1024);

    dim3 g(1024 / BN, 32768 / BM);   // (8, 256)
    gemm_bt<<<g, 256, 0, stream>>>(xb, W0b, b0, Zb, 800, 1024);
    act_kernel<<<8192, 256, 0, stream>>>(Zb, mask1, tids, hb, mo1);
    gemm_bt<<<g, 256, 0, stream>>>(hb, W1b, b1, Zb, 1024, 1024);
    act_kernel<<<8192, 256, 0, stream>>>(Zb, mask2, tids + 1024, hb, mo2);
    gemm_bt<<<g, 256, 0, stream>>>(hb, W2b, b2, Zb, 1024, 1024);
    act_kernel<<<8192, 256, 0, stream>>>(Zb, mask3, tids + 2048, hb, mo3);
    final_layer<<<2048, 256, 0, stream>>>(hb, W3, b3, out);
}

// Round 3
// 1192.732 us; speedup vs baseline: 1.0052x; 1.0052x over previous
//
#include <hip/hip_runtime.h>
#include <hip/hip_bf16.h>
#include <hip/hip_cooperative_groups.h>
#include <cstdint>
#include <cstddef>

namespace cg = cooperative_groups;

typedef __bf16 bf16_t;
typedef bf16_t bf16x8 __attribute__((ext_vector_type(8)));
typedef bf16_t bf16x4 __attribute__((ext_vector_type(4)));
typedef float f32x4 __attribute__((ext_vector_type(4)));

#define NEG_BIG (-1e30f)
#define BM 128
#define BN 128
#define BK 32

// ================= device phase bodies (shared by fused + fallback) =================

__device__ __forceinline__ void convert_row(const float* __restrict__ src,
                                            bf16_t* __restrict__ dst,
                                            int incols, int outcols, int row) {
    const float* s = src + (size_t)row * incols;
    bf16_t* d = dst + (size_t)row * outcols;
    const int n4 = outcols >> 2;
    for (int c = threadIdx.x; c < n4; c += 256) {
        const int col = c << 2;
        float4 v;
        if (col < incols) v = *(const float4*)(s + col);   // incols % 4 == 0
        else              v = make_float4(0.f, 0.f, 0.f, 0.f);
        bf16x4 o;
        o[0] = (bf16_t)v.x; o[1] = (bf16_t)v.y; o[2] = (bf16_t)v.z; o[3] = (bf16_t)v.w;
        *(bf16x4*)(d + col) = o;
    }
}

// one 128x128 tile of Z = A @ W^T + bias; tile index: n-tile = tile&7 (N==1024), m-tile = tile>>3
__device__ __forceinline__ void gemm_tile(char* smem,
                                          const bf16_t* __restrict__ A,
                                          const bf16_t* __restrict__ W,
                                          const float* __restrict__ bias,
                                          bf16_t* __restrict__ Z,
                                          int K, int tile) {
    bf16_t* As = (bf16_t*)smem;            // 128*32*2 = 8 KB
    bf16_t* Bs = (bf16_t*)(smem + 8192);   // 8 KB
    const int tid  = threadIdx.x;
    const int wid  = tid >> 6;
    const int lane = tid & 63;
    const int n0 = (tile & 7) * BN;
    const int m0 = (tile >> 3) * BM;

    const int wm = (wid >> 1) * 64;
    const int wn = (wid & 1) * 64;

    f32x4 acc[4][4] = {};

    const int srow0 = wid * 32 + (lane >> 2);
    const int scol  = (lane & 3) * 8;

    const bf16_t* Aptr0 = A + (size_t)(m0 + srow0) * K + scol;
    const bf16_t* Aptr1 = A + (size_t)(m0 + srow0 + 16) * K + scol;
    const bf16_t* Wptr0 = W + (size_t)(n0 + srow0) * K + scol;
    const bf16_t* Wptr1 = W + (size_t)(n0 + srow0 + 16) * K + scol;

    bf16_t* AsB0 = As + (wid * 2 + 0) * 512;
    bf16_t* AsB1 = As + (wid * 2 + 1) * 512;
    bf16_t* BsB0 = Bs + (wid * 2 + 0) * 512;
    bf16_t* BsB1 = Bs + (wid * 2 + 1) * 512;

    for (int k0 = 0; k0 < K; k0 += BK) {
        __syncthreads();
        __builtin_amdgcn_global_load_lds((const __attribute__((address_space(1))) void*)(Aptr0 + k0),
                                         (__attribute__((address_space(3))) void*)AsB0, 16, 0, 0);
        __builtin_amdgcn_global_load_lds((const __attribute__((address_space(1))) void*)(Aptr1 + k0),
                                         (__attribute__((address_space(3))) void*)AsB1, 16, 0, 0);
        __builtin_amdgcn_global_load_lds((const __attribute__((address_space(1))) void*)(Wptr0 + k0),
                                         (__attribute__((address_space(3))) void*)BsB0, 16, 0, 0);
        __builtin_amdgcn_global_load_lds((const __attribute__((address_space(1))) void*)(Wptr1 + k0),
                                         (__attribute__((address_space(3))) void*)BsB1, 16, 0, 0);
        __syncthreads();

        const int arow = wm + (lane & 15);
        const int brow = wn + (lane & 15);
        const int koff = (lane >> 4) * 8;
        bf16x8 af[4], bfr[4];
        #pragma unroll
        for (int i = 0; i < 4; ++i)
            af[i] = *(const bf16x8*)(As + (arow + i * 16) * BK + koff);
        #pragma unroll
        for (int j = 0; j < 4; ++j)
            bfr[j] = *(const bf16x8*)(Bs + (brow + j * 16) * BK + koff);
        #pragma unroll
        for (int i = 0; i < 4; ++i)
            #pragma unroll
            for (int j = 0; j < 4; ++j)
                acc[i][j] = __builtin_amdgcn_mfma_f32_16x16x32_bf16(af[i], bfr[j], acc[i][j], 0, 0, 0);
    }

    const int cq = lane >> 4;
    const int cl = lane & 15;
    #pragma unroll
    for (int j = 0; j < 4; ++j) {
        const int col = n0 + wn + j * 16 + cl;
        const float bj = bias[col];
        #pragma unroll
        for (int i = 0; i < 4; ++i) {
            const int row = m0 + wm + i * 16 + cq * 4;
            #pragma unroll
            for (int r = 0; r < 4; ++r)
                Z[(size_t)(row + r) * 1024 + col] = (bf16_t)(acc[i][j][r] + bj);
        }
    }
}

__device__ __forceinline__ float wave_max(float v) {
    #pragma unroll
    for (int off = 32; off > 0; off >>= 1) v = fmaxf(v, __shfl_xor(v, off));
    return v;
}
__device__ __forceinline__ float wave_sum(float v) {
    #pragma unroll
    for (int off = 32; off > 0; off >>= 1) v += __shfl_xor(v, off);
    return v;
}

// one group of 4 rows (one per wave); rg = row-group index
__device__ __forceinline__ void act_rows(const bf16_t* __restrict__ Z,
                                         const float* __restrict__ mask,
                                         const int* __restrict__ tids,
                                         bf16_t* __restrict__ H,
                                         float* __restrict__ mask_out, int rg) {
    const int wid  = threadIdx.x >> 6;
    const int lane = threadIdx.x & 63;
    const int row  = rg * 4 + wid;
    const size_t rb = (size_t)row * 1024;

    float z[16], mk[16];
    int   ty[16];
    #pragma unroll
    for (int c = 0; c < 4; ++c) {
        const int col = c * 256 + lane * 4;
        const bf16x4 zv = *(const bf16x4*)(Z + rb + col);
        const float4 mv = *(const float4*)(mask + rb + col);
        const int4   tv = *(const int4*)(tids + col);
        z[c*4+0] = (float)zv[0]; z[c*4+1] = (float)zv[1];
        z[c*4+2] = (float)zv[2]; z[c*4+3] = (float)zv[3];
        mk[c*4+0] = mv.x; mk[c*4+1] = mv.y; mk[c*4+2] = mv.z; mk[c*4+3] = mv.w;
        ty[c*4+0] = tv.x; ty[c*4+1] = tv.y; ty[c*4+2] = tv.z; ty[c*4+3] = tv.w;
    }

    float mx3 = NEG_BIG, mx4 = NEG_BIG;
    #pragma unroll
    for (int j = 0; j < 16; ++j) {
        if (ty[j] == 3) mx3 = fmaxf(mx3, z[j]);
        if (ty[j] == 4) mx4 = fmaxf(mx4, -z[j]);
    }
    mx3 = wave_max(mx3);
    mx4 = wave_max(mx4);

    float s3 = 0.f, s4 = 0.f;
    #pragma unroll
    for (int j = 0; j < 16; ++j) {
        if (ty[j] == 3) s3 += __expf(z[j] - mx3);
        if (ty[j] == 4) s4 += __expf(-z[j] - mx4);
    }
    s3 = wave_sum(s3);
    s4 = wave_sum(s4);
    const float inv3 = 1.f / s3;
    const float inv4 = 1.f / s4;

    #pragma unroll
    for (int c = 0; c < 4; ++c) {
        const int col = c * 256 + lane * 4;
        bf16x4 h4;
        float4 m4;
        #pragma unroll
        for (int j = 0; j < 4; ++j) {
            const int k = c * 4 + j;
            const float zz = z[k];
            const int   tt = ty[k];
            float a;
            if (tt == 0)      a = fmaxf(zz, 0.f);
            else if (tt == 1) { const float e = __expf(-2.f * fabsf(zz));
                                const float th = (1.f - e) / (1.f + e);
                                a = (zz >= 0.f) ? th : -th; }
            else if (tt == 2) a = 1.f / (1.f + __expf(-zz));
            else if (tt == 3) a = __expf(zz - mx3) * inv3;
            else if (tt == 4) a = __expf(-zz - mx4) * inv4;
            else if (tt == 5) a = 0.5f * zz * (1.f + erff(zz * 0.70710678118654752f));
            else              a = (zz >= 0.f) ? zz : 0.01f * zz;
            h4[j] = (bf16_t)(a * mk[k] * 2.0f);   // KEEP_SCALE = 2
        }
        m4.x = mk[c*4+0]; m4.y = mk[c*4+1]; m4.z = mk[c*4+2]; m4.w = mk[c*4+3];
        *(bf16x4*)(H + rb + col) = h4;
        *(float4*)(mask_out + rb + col) = m4;
    }
}

// 16 rows of logits + log_softmax; Ws = bf16 W3 in LDS (10*1024)
__device__ __forceinline__ void final_block(const bf16_t* __restrict__ Ws,
                                            const bf16_t* __restrict__ H,
                                            const float* __restrict__ b3,
                                            float* __restrict__ out, int b) {
    const int wid  = threadIdx.x >> 6;
    const int lane = threadIdx.x & 63;
    #pragma unroll 1
    for (int rr = 0; rr < 4; ++rr) {
        const int row = b * 16 + wid * 4 + rr;
        const bf16_t* hrow = H + (size_t)row * 1024;
        float acc[10];
        #pragma unroll
        for (int n = 0; n < 10; ++n) acc[n] = 0.f;
        #pragma unroll
        for (int c = 0; c < 2; ++c) {
            const int k = c * 512 + lane * 8;
            const bf16x8 hv = *(const bf16x8*)(hrow + k);
            float hf[8];
            #pragma unroll
            for (int j = 0; j < 8; ++j) hf[j] = (float)hv[j];
            #pragma unroll
            for (int n = 0; n < 10; ++n) {
                const bf16x8 wv = *(const bf16x8*)(Ws + n * 1024 + k);
                #pragma unroll
                for (int j = 0; j < 8; ++j) acc[n] += hf[j] * (float)wv[j];
            }
        }
        #pragma unroll
        for (int n = 0; n < 10; ++n)
            #pragma unroll
            for (int off = 32; off > 0; off >>= 1)
                acc[n] += __shfl_down(acc[n], off);
        if (lane == 0) {
            float lg[10]; float mx = -1e30f;
            #pragma unroll
            for (int n = 0; n < 10; ++n) { lg[n] = acc[n] + b3[n]; mx = fmaxf(mx, lg[n]); }
            float se = 0.f;
            #pragma unroll
            for (int n = 0; n < 10; ++n) se += __expf(lg[n] - mx);
            const float lse = logf(se) + mx;
            #pragma unroll
            for (int n = 0; n < 10; ++n) out[(size_t)row * 10 + n] = lg[n] - lse;
        }
    }
}

// ================= persistent cooperative kernel =================

struct FusedParams {
    const float *x, *W0, *b0, *W1, *b1, *W2, *b2, *W3, *b3;
    const float *mask1, *mask2, *mask3;
    const int* tids;
    bf16_t *xb, *W0b, *W1b, *W2b, *Zb, *hb;
    float *out, *mo1, *mo2, *mo3;
};

__global__ __launch_bounds__(256) void fused_forward(FusedParams p) {
    cg::grid_group grid = cg::this_grid();
    __shared__ __align__(16) char smem[20480];
    const int nb  = gridDim.x;
    const int bid = blockIdx.x;

    // P0: fp32->bf16 converts (with K padding for layer 0)
    for (int r = bid; r < 32768; r += nb) convert_row(p.x,  p.xb,  784, 800, r);
    for (int r = bid; r < 1024;  r += nb) convert_row(p.W0, p.W0b, 784, 800, r);
    for (int r = bid; r < 1024;  r += nb) convert_row(p.W1, p.W1b, 1024, 1024, r);
    for (int r = bid; r < 1024;  r += nb) convert_row(p.W2, p.W2b, 1024, 1024, r);
    grid.sync();
    // P1: layer-0 GEMM
    for (int t = bid; t < 2048; t += nb) gemm_tile(smem, p.xb, p.W0b, p.b0, p.Zb, 800, t);
    grid.sync();
    // P2: act 1
    for (int r = bid; r < 8192; r += nb) act_rows(p.Zb, p.mask1, p.tids, p.hb, p.mo1, r);
    grid.sync();
    // P3: layer-1 GEMM
    for (int t = bid; t < 2048; t += nb) gemm_tile(smem, p.hb, p.W1b, p.b1, p.Zb, 1024, t);
    grid.sync();
    // P4: act 2
    for (int r = bid; r < 8192; r += nb) act_rows(p.Zb, p.mask2, p.tids + 1024, p.hb, p.mo2, r);
    grid.sync();
    // P5: layer-2 GEMM
    for (int t = bid; t < 2048; t += nb) gemm_tile(smem, p.hb, p.W2b, p.b2, p.Zb, 1024, t);
    grid.sync();
    // P6: act 3
    for (int r = bid; r < 8192; r += nb) act_rows(p.Zb, p.mask3, p.tids + 2048, p.hb, p.mo3, r);
    grid.sync();
    // P7: final layer + log_softmax
    {
        bf16_t* Ws = (bf16_t*)smem;
        for (int i = threadIdx.x; i < 10240; i += 256) Ws[i] = (bf16_t)p.W3[i];
        __syncthreads();
        for (int b = bid; b < 2048; b += nb) final_block(Ws, p.hb, p.b3, p.out, b);
    }
}

// ================= fallback standalone kernels (exact R2 behavior) =================

__global__ __launch_bounds__(256) void convert_pad(const float* __restrict__ src,
                                                   bf16_t* __restrict__ dst,
                                                   int incols, int outcols) {
    convert_row(src, dst, incols, outcols, blockIdx.x);
}

__global__ __launch_bounds__(256) void gemm_bt(const bf16_t* __restrict__ A,
                                               const bf16_t* __restrict__ W,
                                               const float* __restrict__ bias,
                                               bf16_t* __restrict__ Z, int K) {
    __shared__ __align__(16) char smem[16384];
    gemm_tile(smem, A, W, bias, Z, K, blockIdx.y * 8 + blockIdx.x);
}

__global__ __launch_bounds__(256) void act_kernel(const bf16_t* __restrict__ Z,
                                                  const float* __restrict__ mask,
                                                  const int* __restrict__ tids,
                                                  bf16_t* __restrict__ H,
                                                  float* __restrict__ mask_out) {
    act_rows(Z, mask, tids, H, mask_out, blockIdx.x);
}

__global__ __launch_bounds__(256) void final_layer(const bf16_t* __restrict__ H,
                                                   const float* __restrict__ W3,
                                                   const float* __restrict__ b3,
                                                   float* __restrict__ out) {
    __shared__ __align__(16) bf16_t Ws[10 * 1024];
    for (int i = threadIdx.x; i < 10240; i += 256) Ws[i] = (bf16_t)W3[i];
    __syncthreads();
    final_block(Ws, H, b3, out, blockIdx.x);
}

// ================= launch =================

extern "C" void kernel_launch(void* const* d_in, const int* in_sizes, int n_in,
                              void* d_out, int out_size, void* d_ws, size_t ws_size,
                              hipStream_t stream) {
    (void)in_sizes; (void)n_in; (void)out_size; (void)ws_size;
    FusedParams p;
    p.x     = (const float*)d_in[0];
    p.W0    = (const float*)d_in[1];
    p.b0    = (const float*)d_in[2];
    p.W1    = (const float*)d_in[3];
    p.b1    = (const float*)d_in[4];
    p.W2    = (const float*)d_in[5];
    p.b2    = (const float*)d_in[6];
    p.W3    = (const float*)d_in[7];
    p.b3    = (const float*)d_in[8];
    p.mask1 = (const float*)d_in[9];
    p.mask2 = (const float*)d_in[10];
    p.mask3 = (const float*)d_in[11];
    p.tids  = (const int*)d_in[12];

    p.out = (float*)d_out;
    p.mo1 = p.out + 327680;
    p.mo2 = p.mo1 + 33554432;
    p.mo3 = p.mo2 + 33554432;

    char* ws = (char*)d_ws;
    p.xb  = (bf16_t*)ws;  ws += (size_t)32768 * 800 * 2;
    p.W0b = (bf16_t*)ws;  ws += (size_t)1024 * 800 * 2;
    p.W1b = (bf16_t*)ws;  ws += (size_t)1024 * 1024 * 2;
    p.W2b = (bf16_t*)ws;  ws += (size_t)1024 * 1024 * 2;
    p.Zb  = (bf16_t*)ws;  ws += (size_t)32768 * 1024 * 2;
    p.hb  = (bf16_t*)ws;  ws += (size_t)32768 * 1024 * 2;

    // Try the persistent cooperative path; fall back to multi-kernel on any failure.
    int perCU = 0;
    hipError_t oerr = hipOccupancyMaxActiveBlocksPerMultiprocessor(
        &perCU, (const void*)fused_forward, 256, 0);
    bool launched = false;
    if (oerr == hipSuccess && perCU >= 1) {
        int blocks = perCU * 256;          // MI355X: 256 CUs
        if (blocks > 2048) blocks = 2048;
        void* kargs[] = { (void*)&p };
        hipError_t lerr = hipLaunchCooperativeKernel(
            (const void*)fused_forward, dim3(blocks), dim3(256), kargs, 0, stream);
        if (lerr == hipSuccess) launched = true;
        else (void)hipGetLastError();      // clear error state for fallback
    } else {
        (void)hipGetLastError();
    }

    if (!launched) {
        convert_pad<<<32768, 256, 0, stream>>>(p.x,  p.xb,  784, 800);
        convert_pad<<<1024,  256, 0, stream>>>(p.W0, p.W0b, 784, 800);
        convert_pad<<<1024,  256, 0, stream>>>(p.W1, p.W1b, 1024, 1024);
        convert_pad<<<1024,  256, 0, stream>>>(p.W2, p.W2b, 1024, 1024);
        dim3 g(8, 256);
        gemm_bt<<<g, 256, 0, stream>>>(p.xb, p.W0b, p.b0, p.Zb, 800);
        act_kernel<<<8192, 256, 0, stream>>>(p.Zb, p.mask1, p.tids, p.hb, p.mo1);
        gemm_bt<<<g, 256, 0, stream>>>(p.hb, p.W1b, p.b1, p.Zb, 1024);
        act_kernel<<<8192, 256, 0, stream>>>(p.Zb, p.mask2, p.tids + 1024, p.hb, p.mo2);
        gemm_bt<<<g, 256, 0, stream>>>(p.hb, p.W2b, p.b2, p.Zb, 1024);
        act_kernel<<<8192, 256, 0, stream>>>(p.Zb, p.mask3, p.tids + 2048, p.hb, p.mo3);
        final_layer<<<2048, 256, 0, stream>>>(p.hb, p.W3, p.b3, p.out);
    }
}